// Round 1
// baseline (427.057 us; speedup 1.0000x reference)
//
#include <hip/hip_runtime.h>
#include <hip/hip_bf16.h>

// Cost volume: out[b, i*9+j, h, w] = (1/C) * sum_c f1[b,c,h,w] * f2pad[b,c,h+i-4, w+j-4]
// B=8 C=128 H=128 W=256, d=4 -> 81 shifts, fp32 in/out.

#define Bn 8
#define Cn 128
#define Hn 128
#define Wn 256
#define Dp 4
#define NSHIFT 81
#define TH 8            // h rows per block
#define TW 64           // w cols per block
#define CC 8            // channels per chunk
#define NCHUNK (Cn / CC)          // 16
#define FR (TH + 2 * Dp)          // 16 f2 tile rows
#define FC (TW + 2 * Dp)          // 72 f2 tile cols
#define NTHREADS 384
#define NBLOCKS (Bn * (Hn / TH) * (Wn / TW))   // 512

__device__ __forceinline__ float bflo(unsigned int u) {
    union { unsigned int i; float f; } x; x.i = u << 16; return x.f;
}
__device__ __forceinline__ float bfhi(unsigned int u) {
    union { unsigned int i; float f; } x; x.i = u & 0xffff0000u; return x.f;
}
__device__ __forceinline__ unsigned short f2b(float f) {
    __hip_bfloat16 h = __float2bfloat16(f);   // RTNE
    union { __hip_bfloat16 h; unsigned short u; } x; x.h = h; return x.u;
}

__global__ __launch_bounds__(NTHREADS, 2)
void costvol_kernel(const float* __restrict__ f1,
                    const float* __restrict__ f2,
                    float* __restrict__ out)
{
    // bf16 f2 tile: row pitch 144 B -> thread b64 reads at 8p byte stride: dense, conflict-free
    __shared__ unsigned short s_f2[CC][FR][FC];
    __shared__ float s_f1[CC][TH][TW];

    const int tid = threadIdx.x;

    // XCD-bijective swizzle: 512 blocks, %8==0. Each XCD gets one full batch image b
    // -> f2 halo re-reads between h/w-neighboring blocks hit that XCD's L2.
    const int hw = blockIdx.x;
    const int logical = (hw & 7) * (NBLOCKS / 8) + (hw >> 3);
    const int ht = logical & 15;           // Hn/TH = 16 tiles
    const int wt = (logical >> 4) & 3;     // Wn/TW = 4 tiles
    const int bb = logical >> 6;           // batch
    const int h0 = ht * TH;
    const int w0 = wt * TW;

    // compute-role decomposition: g = dy-group (3 dys each), r = row, p = 4-px group
    const int g = tid / 128;       // 0..2
    const int rem = tid % 128;
    const int r = rem / 16;        // 0..7
    const int p = rem % 16;        // 0..15  -> w = w0 + 4p + {0..3}

    float acc[3][9][4];
#pragma unroll
    for (int a = 0; a < 3; ++a)
#pragma unroll
        for (int b2 = 0; b2 < 9; ++b2)
#pragma unroll
            for (int c2 = 0; c2 < 4; ++c2) acc[a][b2][c2] = 0.0f;

    // ---- staging index precompute (constant across chunks) ----
    // f2: CC*FR*(FC/4) = 8*16*18 = 2304 float4 loads, 6 per thread
    int f2_goff[6];     // element offset within (bb, channel f2c) plane + channel-plane base
    int f2_loff[6];     // LDS ushort offset
    bool f2_ok[6];
#pragma unroll
    for (int it = 0; it < 6; ++it) {
        const int idx = tid + NTHREADS * it;          // < 2304
        const int c = idx / 288;                      // 0..7
        const int rr = idx % 288;
        const int row = rr / 18;                      // 0..15
        const int q = rr % 18;                        // 0..17
        const int gh = h0 + row - Dp;
        const int gw = w0 + 4 * q - Dp;
        f2_ok[it] = (gh >= 0 && gh < Hn && gw >= 0 && gw < Wn);
        f2_goff[it] = ((bb * Cn + c) * Hn + gh) * Wn + gw;   // add (chunk*CC)*Hn*Wn later
        f2_loff[it] = (c * FR + row) * FC + 4 * q;
    }
    // f1: CC*TH*(TW/4) = 8*8*16 = 1024 float4 loads, <=3 per thread
    int f1_goff[3];
    int f1_loff[3];
#pragma unroll
    for (int it = 0; it < 3; ++it) {
        const int idx = tid + NTHREADS * it;
        const int i2 = (idx < 1024) ? idx : 0;        // threads 256..383 skip it==2
        const int c = i2 >> 7;
        const int rr = i2 & 127;
        const int row = rr >> 4;
        const int q = rr & 15;
        f1_goff[it] = ((bb * Cn + c) * Hn + (h0 + row)) * Wn + (w0 + 4 * q);
        f1_loff[it] = (c * TH + row) * TW + 4 * q;
    }

    float4 pf2[6];
    float4 pf1[3];

    // prologue: load chunk 0 into regs
    {
        const int cb = 0;
#pragma unroll
        for (int it = 0; it < 6; ++it)
            pf2[it] = f2_ok[it] ? *(const float4*)(f2 + cb + f2_goff[it])
                                : make_float4(0.f, 0.f, 0.f, 0.f);
#pragma unroll
        for (int it = 0; it < 3; ++it)
            if (tid + NTHREADS * it < 1024)
                pf1[it] = *(const float4*)(f1 + cb + f1_goff[it]);
    }

    for (int chunk = 0; chunk < NCHUNK; ++chunk) {
        __syncthreads();   // previous compute done reading LDS
        // regs -> LDS (convert f2 to bf16)
#pragma unroll
        for (int it = 0; it < 6; ++it) {
            uint2 o;
            o.x = (unsigned)f2b(pf2[it].x) | ((unsigned)f2b(pf2[it].y) << 16);
            o.y = (unsigned)f2b(pf2[it].z) | ((unsigned)f2b(pf2[it].w) << 16);
            *(uint2*)((unsigned short*)s_f2 + f2_loff[it]) = o;
        }
#pragma unroll
        for (int it = 0; it < 3; ++it)
            if (tid + NTHREADS * it < 1024)
                *(float4*)((float*)s_f1 + f1_loff[it]) = pf1[it];
        __syncthreads();

        // prefetch next chunk while computing this one
        if (chunk + 1 < NCHUNK) {
            const int cb = (chunk + 1) * CC * Hn * Wn;
#pragma unroll
            for (int it = 0; it < 6; ++it)
                pf2[it] = f2_ok[it] ? *(const float4*)(f2 + cb + f2_goff[it])
                                    : make_float4(0.f, 0.f, 0.f, 0.f);
#pragma unroll
            for (int it = 0; it < 3; ++it)
                if (tid + NTHREADS * it < 1024)
                    pf1[it] = *(const float4*)(f1 + cb + f1_goff[it]);
        }

        // ---- compute: 8 channels x 3 dy-rows x (9 dx x 4 px) FMAs ----
#pragma unroll 1
        for (int c = 0; c < CC; ++c) {
            const float4 f1v = *(const float4*)&s_f1[c][r][4 * p];
#pragma unroll
            for (int dyi = 0; dyi < 3; ++dyi) {
                const int row = r + 3 * g + dyi;              // 0..15
                const unsigned short* base = &s_f2[c][row][4 * p];
                const uint2 t0 = *(const uint2*)(base);
                const uint2 t1 = *(const uint2*)(base + 4);
                const uint2 t2 = *(const uint2*)(base + 8);
                float win[12];
                win[0] = bflo(t0.x);  win[1] = bfhi(t0.x);
                win[2] = bflo(t0.y);  win[3] = bfhi(t0.y);
                win[4] = bflo(t1.x);  win[5] = bfhi(t1.x);
                win[6] = bflo(t1.y);  win[7] = bfhi(t1.y);
                win[8] = bflo(t2.x);  win[9] = bfhi(t2.x);
                win[10] = bflo(t2.y); win[11] = bfhi(t2.y);
#pragma unroll
                for (int j = 0; j < 9; ++j) {
                    acc[dyi][j][0] += f1v.x * win[0 + j];
                    acc[dyi][j][1] += f1v.y * win[1 + j];
                    acc[dyi][j][2] += f1v.z * win[2 + j];
                    acc[dyi][j][3] += f1v.w * win[3 + j];
                }
            }
        }
    }

    // epilogue: scale by 1/C, write 27 shifts x 4 px as float4
    const float scale = 1.0f / (float)Cn;
#pragma unroll
    for (int dyi = 0; dyi < 3; ++dyi) {
#pragma unroll
        for (int j = 0; j < 9; ++j) {
            const int s = (3 * g + dyi) * 9 + j;
            float4 v;
            v.x = acc[dyi][j][0] * scale;
            v.y = acc[dyi][j][1] * scale;
            v.z = acc[dyi][j][2] * scale;
            v.w = acc[dyi][j][3] * scale;
            float* dst = out + (((size_t)(bb * NSHIFT + s) * Hn + (h0 + r)) * Wn + (w0 + 4 * p));
            *(float4*)dst = v;
        }
    }
}

extern "C" void kernel_launch(void* const* d_in, const int* in_sizes, int n_in,
                              void* d_out, int out_size, void* d_ws, size_t ws_size,
                              hipStream_t stream) {
    const float* f1 = (const float*)d_in[0];
    const float* f2 = (const float*)d_in[1];
    float* out = (float*)d_out;
    (void)in_sizes; (void)n_in; (void)out_size; (void)d_ws; (void)ws_size;
    costvol_kernel<<<NBLOCKS, NTHREADS, 0, stream>>>(f1, f2, out);
}